// Round 4
// baseline (518.377 us; speedup 1.0000x reference)
//
#include <hip/hip_runtime.h>
#include <hip/hip_bf16.h>

// GIN: 3x [agg = segment_sum(h[src], dst); r = h + agg; h = relu(r@Wa+ba)@Wb+bb]
// then mean over nodes @ Wout + bout -> [1,16]
//
// R4: CSR build rewritten as binned counting sort (bin = dst>>5, 32 nodes/bin,
// 1563 bins). Scatter writes land in an L2-resident ~100KB frontier -> no
// write amplification (R3's fill_kernel wrote 52MB for 3.2MB payload).
// rowptr is produced by the per-bin sort (hist/scan/finalize kernels deleted).
// agg: quarter-wave (16 lanes x uint2) bf16 gather, unroll 4. MLP: LDS tile.

#define NNODES 50000
#define NEDGES 800000
#define DDIM   64
#define DOUT   16
#define NBIN   1563          // ceil(50000/32)
#define NBIN_PAD 1568

typedef unsigned int uint;

// fp32 -> bf16 RNE (bit trick)
static __device__ __forceinline__ uint f2bf(float f) {
    uint u = __float_as_uint(f);
    return (u + 0x7fffu + ((u >> 16) & 1u)) >> 16;
}
static __device__ __forceinline__ float bf_lo(uint u) { return __uint_as_float(u << 16); }
static __device__ __forceinline__ float bf_hi(uint u) { return __uint_as_float(u & 0xffff0000u); }

// ---------------- binned CSR build ----------------

__global__ void zero_bins_kernel(int* bin_cnt, int* bin_cursor) {
    int i = blockIdx.x * 256 + threadIdx.x;
    if (i < NBIN_PAD) { bin_cnt[i] = 0; bin_cursor[i] = 0; }
}

__global__ void bin_count_kernel(const int* __restrict__ dst, int* __restrict__ bin_cnt, int n) {
    int i = blockIdx.x * 256 + threadIdx.x;
    if (i < n) atomicAdd(&bin_cnt[dst[i] >> 5], 1);
}

// single block: exclusive scan of bin counts -> bin_base; also rowptr[N] = E
__global__ __launch_bounds__(256) void bin_scan_kernel(const int* __restrict__ bin_cnt,
                                                       int* __restrict__ bin_base,
                                                       int* __restrict__ rowptr) {
    __shared__ int s[256];
    __shared__ int carry;
    if (threadIdx.x == 0) carry = 0;
    __syncthreads();
    for (int c = 0; c < NBIN_PAD; c += 256) {
        int i = c + threadIdx.x;
        int v = (i < NBIN_PAD) ? bin_cnt[i] : 0;
        s[threadIdx.x] = v;
        __syncthreads();
        for (int off = 1; off < 256; off <<= 1) {
            int add = (threadIdx.x >= off) ? s[threadIdx.x - off] : 0;
            __syncthreads();
            s[threadIdx.x] += add;
            __syncthreads();
        }
        if (i < NBIN_PAD) bin_base[i] = carry + s[threadIdx.x] - v;  // exclusive
        __syncthreads();
        if (threadIdx.x == 0) carry += s[255];
        __syncthreads();
    }
    if (threadIdx.x == 0) rowptr[NNODES] = NEDGES;
}

// scatter edges into per-bin regions; val packs src (16b) + dst-within-bin (5b)
__global__ void bin_scatter_kernel(const int* __restrict__ src, const int* __restrict__ dst,
                                   const int* __restrict__ bin_base, int* __restrict__ bin_cursor,
                                   uint* __restrict__ binbuf, int n) {
    int i = blockIdx.x * 256 + threadIdx.x;
    if (i < n) {
        int d = dst[i];
        int b = d >> 5;
        int pos = atomicAdd(&bin_cursor[b], 1);
        binbuf[bin_base[b] + pos] = (uint)src[i] | ((uint)(d & 31) << 16);
    }
}

// one block per bin: 32-counter LDS hist -> scan -> write rowptr + sorted csr
__global__ __launch_bounds__(256) void bin_sort_kernel(const uint* __restrict__ binbuf,
                                                       const int* __restrict__ bin_cnt,
                                                       const int* __restrict__ bin_base,
                                                       int* __restrict__ rowptr,
                                                       int* __restrict__ csr, int n) {
    __shared__ int hist[32];
    __shared__ int excl[32];
    __shared__ int cursor[32];
    int b = blockIdx.x;
    int t = threadIdx.x;
    int cnt = bin_cnt[b];
    int base = bin_base[b];
    if (t < 32) hist[t] = 0;
    __syncthreads();
    for (int i = t; i < cnt; i += 256) {
        uint v = binbuf[base + i];
        atomicAdd(&hist[v >> 16], 1);
    }
    __syncthreads();
    if (t == 0) {
        int run = 0;
        for (int i = 0; i < 32; i++) { int c = hist[i]; excl[i] = run; cursor[i] = run; run += c; }
    }
    __syncthreads();
    if (t < 32) {
        int node = (b << 5) + t;
        if (node < n) rowptr[node] = base + excl[t];
    }
    for (int i = t; i < cnt; i += 256) {
        uint v = binbuf[base + i];
        int pos = atomicAdd(&cursor[v >> 16], 1);
        csr[base + pos] = (int)(v & 0xffffu);
    }
}

// ---------------- features fp32 -> bf16 ----------------

__global__ void cvt_kernel(const float2* __restrict__ in, uint* __restrict__ out, int n2) {
    int i = blockIdx.x * 256 + threadIdx.x;
    if (i < n2) {
        float2 v = in[i];
        out[i] = f2bf(v.x) | (f2bf(v.y) << 16);
    }
}

// ---------------- aggregation (bf16): r[n] = h[n] + sum_{e in(n)} h[src[e]] ----------------
// quarter-wave per node: 16 lanes, each owns one uint2 (4 dims). Unroll 4.

__global__ __launch_bounds__(256) void agg_kernel(const uint2* __restrict__ h64,
                                                  const int* __restrict__ rowptr,
                                                  const int* __restrict__ csr,
                                                  uint2* __restrict__ r64, int n) {
    int idx = blockIdx.x * 256 + threadIdx.x;
    int node = idx >> 4;
    int p = idx & 15;
    if (node >= n) return;
    uint2 u = h64[(size_t)node * 16 + p];
    float a0 = bf_lo(u.x), a1 = bf_hi(u.x), a2 = bf_lo(u.y), a3 = bf_hi(u.y);
    int e = rowptr[node], end = rowptr[node + 1];
    for (; e + 3 < end; e += 4) {
        int s0 = csr[e], s1 = csr[e + 1], s2 = csr[e + 2], s3 = csr[e + 3];
        uint2 u0 = h64[(size_t)s0 * 16 + p];
        uint2 u1 = h64[(size_t)s1 * 16 + p];
        uint2 u2 = h64[(size_t)s2 * 16 + p];
        uint2 u3 = h64[(size_t)s3 * 16 + p];
        a0 += bf_lo(u0.x); a1 += bf_hi(u0.x); a2 += bf_lo(u0.y); a3 += bf_hi(u0.y);
        a0 += bf_lo(u1.x); a1 += bf_hi(u1.x); a2 += bf_lo(u1.y); a3 += bf_hi(u1.y);
        a0 += bf_lo(u2.x); a1 += bf_hi(u2.x); a2 += bf_lo(u2.y); a3 += bf_hi(u2.y);
        a0 += bf_lo(u3.x); a1 += bf_hi(u3.x); a2 += bf_lo(u3.y); a3 += bf_hi(u3.y);
    }
    for (; e < end; e++) {
        uint2 u0 = h64[(size_t)csr[e] * 16 + p];
        a0 += bf_lo(u0.x); a1 += bf_hi(u0.x); a2 += bf_lo(u0.y); a3 += bf_hi(u0.y);
    }
    r64[(size_t)node * 16 + p] =
        make_uint2(f2bf(a0) | (f2bf(a1) << 16), f2bf(a2) | (f2bf(a3) << 16));
}

// ---------------- MLP: out = relu(r@Wa+ba)@Wb+bb  (bf16 in/out) ----------------

__global__ __launch_bounds__(256) void mlp_kernel(const uint2* __restrict__ r64,
                                                  const float* __restrict__ Wa,
                                                  const float* __restrict__ ba,
                                                  const float* __restrict__ Wb,
                                                  const float* __restrict__ bb,
                                                  uint2* __restrict__ out64, int n) {
    __shared__ float sA[64][64];   // Wa[k][j]
    __shared__ float sB[64][64];   // Wb[k][j]
    __shared__ float sR[64][65];   // input tile, reused as hidden tile
    __shared__ float sba[64], sbb[64];

    int t = threadIdx.x;
    for (int i = t; i < 1024; i += 256) {
        ((float4*)sA)[i] = ((const float4*)Wa)[i];
        ((float4*)sB)[i] = ((const float4*)Wb)[i];
    }
    if (t < 64) { sba[t] = ba[t]; sbb[t] = bb[t]; }

    int node0 = blockIdx.x * 64;
    for (int i = t; i < 1024; i += 256) {
        int row = i >> 4;       // 0..63
        int q   = i & 15;       // uint2 index within row
        int gr = node0 + row;
        uint2 v = make_uint2(0u, 0u);
        if (gr < n) v = r64[(size_t)gr * 16 + q];
        sR[row][4 * q + 0] = bf_lo(v.x);
        sR[row][4 * q + 1] = bf_hi(v.x);
        sR[row][4 * q + 2] = bf_lo(v.y);
        sR[row][4 * q + 3] = bf_hi(v.y);
    }
    __syncthreads();

    int tx = t & 15;            // output-col group: j0 = tx*4
    int ty = t >> 4;            // node-row group:  i0 = ty*4
    int j0 = tx * 4, i0 = ty * 4;

    float acc[4][4];
#pragma unroll
    for (int a = 0; a < 4; a++)
#pragma unroll
        for (int b = 0; b < 4; b++) acc[a][b] = 0.f;

#pragma unroll 8
    for (int k = 0; k < 64; k++) {
        float a0 = sR[i0 + 0][k];
        float a1 = sR[i0 + 1][k];
        float a2 = sR[i0 + 2][k];
        float a3 = sR[i0 + 3][k];
        float4 bv = *(const float4*)&sA[k][j0];
        acc[0][0] += a0 * bv.x; acc[0][1] += a0 * bv.y; acc[0][2] += a0 * bv.z; acc[0][3] += a0 * bv.w;
        acc[1][0] += a1 * bv.x; acc[1][1] += a1 * bv.y; acc[1][2] += a1 * bv.z; acc[1][3] += a1 * bv.w;
        acc[2][0] += a2 * bv.x; acc[2][1] += a2 * bv.y; acc[2][2] += a2 * bv.z; acc[2][3] += a2 * bv.w;
        acc[3][0] += a3 * bv.x; acc[3][1] += a3 * bv.y; acc[3][2] += a3 * bv.z; acc[3][3] += a3 * bv.w;
    }
    __syncthreads();   // all reads of sR done before overwrite

#pragma unroll
    for (int a = 0; a < 4; a++)
#pragma unroll
        for (int b = 0; b < 4; b++)
            sR[i0 + a][j0 + b] = fmaxf(acc[a][b] + sba[j0 + b], 0.f);
    __syncthreads();

#pragma unroll
    for (int a = 0; a < 4; a++)
#pragma unroll
        for (int b = 0; b < 4; b++) acc[a][b] = 0.f;

#pragma unroll 8
    for (int k = 0; k < 64; k++) {
        float a0 = sR[i0 + 0][k];
        float a1 = sR[i0 + 1][k];
        float a2 = sR[i0 + 2][k];
        float a3 = sR[i0 + 3][k];
        float4 bv = *(const float4*)&sB[k][j0];
        acc[0][0] += a0 * bv.x; acc[0][1] += a0 * bv.y; acc[0][2] += a0 * bv.z; acc[0][3] += a0 * bv.w;
        acc[1][0] += a1 * bv.x; acc[1][1] += a1 * bv.y; acc[1][2] += a1 * bv.z; acc[1][3] += a1 * bv.w;
        acc[2][0] += a2 * bv.x; acc[2][1] += a2 * bv.y; acc[2][2] += a2 * bv.z; acc[2][3] += a2 * bv.w;
        acc[3][0] += a3 * bv.x; acc[3][1] += a3 * bv.y; acc[3][2] += a3 * bv.z; acc[3][3] += a3 * bv.w;
    }

#pragma unroll
    for (int a = 0; a < 4; a++) {
        int gr = node0 + i0 + a;
        if (gr < n) {
            uint q0 = f2bf(acc[a][0] + sbb[j0 + 0]) | (f2bf(acc[a][1] + sbb[j0 + 1]) << 16);
            uint q1 = f2bf(acc[a][2] + sbb[j0 + 2]) | (f2bf(acc[a][3] + sbb[j0 + 3]) << 16);
            out64[(size_t)gr * 16 + tx] = make_uint2(q0, q1);
        }
    }
}

// ---------------- mean pool (2 stages, bf16 input) + final linear ----------------

__global__ __launch_bounds__(256) void colsum_part_kernel(const uint* __restrict__ h32,
                                                          float* __restrict__ part, int n) {
    __shared__ float red[8][64];
    int t = threadIdx.x;
    int g = t >> 5, p = t & 31;
    float a0 = 0.f, a1 = 0.f;
    for (int i = blockIdx.x * 8 + g; i < n; i += gridDim.x * 8) {
        uint u = h32[(size_t)i * 32 + p];
        a0 += bf_lo(u);
        a1 += bf_hi(u);
    }
    red[g][2 * p]     = a0;
    red[g][2 * p + 1] = a1;
    __syncthreads();
    if (t < 64) {
        float s = 0.f;
        for (int gg = 0; gg < 8; gg++) s += red[gg][t];
        part[blockIdx.x * 64 + t] = s;
    }
}

__global__ __launch_bounds__(64) void final_kernel(const float* __restrict__ part,
                                                   const float* __restrict__ Wout,
                                                   const float* __restrict__ bout,
                                                   float* __restrict__ out, int nparts) {
    __shared__ float cs[64];
    int t = threadIdx.x;
    float s = 0.f;
    for (int b = 0; b < nparts; b++) s += part[b * 64 + t];
    cs[t] = s * (1.0f / (float)NNODES);
    __syncthreads();
    if (t < DOUT) {
        float o = bout[t];
        for (int d = 0; d < DDIM; d++) o += cs[d] * Wout[d * DOUT + t];
        out[t] = o;
    }
}

// ---------------- launch ----------------

extern "C" void kernel_launch(void* const* d_in, const int* in_sizes, int n_in,
                              void* d_out, int out_size, void* d_ws, size_t ws_size,
                              hipStream_t stream) {
    const float* features = (const float*)d_in[0];
    const int*   src      = (const int*)d_in[1];
    const int*   dst      = (const int*)d_in[2];
    const float* W0a = (const float*)d_in[3];  const float* b0a = (const float*)d_in[4];
    const float* W0b = (const float*)d_in[5];  const float* b0b = (const float*)d_in[6];
    const float* W1a = (const float*)d_in[7];  const float* b1a = (const float*)d_in[8];
    const float* W1b = (const float*)d_in[9];  const float* b1b = (const float*)d_in[10];
    const float* W2a = (const float*)d_in[11]; const float* b2a = (const float*)d_in[12];
    const float* W2b = (const float*)d_in[13]; const float* b2b = (const float*)d_in[14];
    const float* Wout = (const float*)d_in[15]; const float* bout = (const float*)d_in[16];
    float* out = (float*)d_out;

    // workspace layout (16B-aligned segments)
    int* bin_cnt    = (int*)d_ws;               // [1568]
    int* bin_cursor = bin_cnt + NBIN_PAD;       // [1568]
    int* bin_base   = bin_cursor + NBIN_PAD;    // [1568]
    int* rowptr     = bin_base + NBIN_PAD;      // [50016] (50001 used)
    uint* binbuf    = (uint*)(rowptr + 50016);  // [800000]
    int* csr        = (int*)(binbuf + 800000);  // [800000]
    uint* hb0       = (uint*)(csr + 800000);    // bf16 h ping [50000*32]
    uint* hb1       = hb0 + NNODES * 32;        // bf16 h pong
    uint* rb        = hb1 + NNODES * 32;        // bf16 r buffer
    float* part     = (float*)(rb + NNODES * 32); // [128*64]

    const int NB_E = (NEDGES + 255) / 256;   // 3125

    // binned CSR build
    zero_bins_kernel<<<(NBIN_PAD + 255) / 256, 256, 0, stream>>>(bin_cnt, bin_cursor);
    bin_count_kernel<<<NB_E, 256, 0, stream>>>(dst, bin_cnt, NEDGES);
    bin_scan_kernel<<<1, 256, 0, stream>>>(bin_cnt, bin_base, rowptr);
    bin_scatter_kernel<<<NB_E, 256, 0, stream>>>(src, dst, bin_base, bin_cursor, binbuf, NEDGES);
    bin_sort_kernel<<<NBIN, 256, 0, stream>>>(binbuf, bin_cnt, bin_base, rowptr, csr, NNODES);

    // features -> bf16
    cvt_kernel<<<(NNODES * 32 + 255) / 256, 256, 0, stream>>>((const float2*)features, hb0, NNODES * 32);

    const int AGG_BLOCKS = (NNODES * 16 + 255) / 256;  // 3125 (16 lanes/node)
    const int MLP_BLOCKS = (NNODES + 63) / 64;         // 782

    // layer 0
    agg_kernel<<<AGG_BLOCKS, 256, 0, stream>>>((const uint2*)hb0, rowptr, csr, (uint2*)rb, NNODES);
    mlp_kernel<<<MLP_BLOCKS, 256, 0, stream>>>((const uint2*)rb, W0a, b0a, W0b, b0b, (uint2*)hb1, NNODES);
    // layer 1
    agg_kernel<<<AGG_BLOCKS, 256, 0, stream>>>((const uint2*)hb1, rowptr, csr, (uint2*)rb, NNODES);
    mlp_kernel<<<MLP_BLOCKS, 256, 0, stream>>>((const uint2*)rb, W1a, b1a, W1b, b1b, (uint2*)hb0, NNODES);
    // layer 2
    agg_kernel<<<AGG_BLOCKS, 256, 0, stream>>>((const uint2*)hb0, rowptr, csr, (uint2*)rb, NNODES);
    mlp_kernel<<<MLP_BLOCKS, 256, 0, stream>>>((const uint2*)rb, W2a, b2a, W2b, b2b, (uint2*)hb1, NNODES);

    // mean pool + final linear
    colsum_part_kernel<<<128, 256, 0, stream>>>(hb1, part, NNODES);
    final_kernel<<<1, 64, 0, stream>>>(part, Wout, bout, out, 128);
}

// Round 5
// 314.027 us; speedup vs baseline: 1.6507x; 1.6507x over previous
//
#include <hip/hip_runtime.h>
#include <hip/hip_bf16.h>

// GIN: 3x [agg = segment_sum(h[src], dst); r = h + agg; h = relu(r@Wa+ba)@Wb+bb]
// then mean over nodes @ Wout + bout -> [1,16]
//
// R5: CSR build = 2-pass MSD bucket sort with NO global atomics and
// one-block-owned output lines (R4 lesson: global-cursor scatter interleaves
// one line's slots across XCDs; non-coherent per-XCD L2s flush partial lines
// -> write amplification survives. Per-block offset runs fix both contention
// and amplification). Sorted key array (dst<<16|src) doubles as csr.
// agg: quarter-wave bf16 gather, unroll 8. MLP: LDS tile (unchanged).

#define NNODES 50000
#define NEDGES 800000
#define DDIM   64
#define DOUT   16

#define CHUNK  4096
#define NB1    196           // ceil(800000/4096)
#define NBUCK  196           // ceil(50000/256), bucket = dst>>8

typedef unsigned int uint;

// fp32 -> bf16 RNE (bit trick)
static __device__ __forceinline__ uint f2bf(float f) {
    uint u = __float_as_uint(f);
    return (u + 0x7fffu + ((u >> 16) & 1u)) >> 16;
}
static __device__ __forceinline__ float bf_lo(uint u) { return __uint_as_float(u << 16); }
static __device__ __forceinline__ float bf_hi(uint u) { return __uint_as_float(u & 0xffff0000u); }

// ---------------- edge sort (2-pass MSD bucket sort) ----------------

// S1: pack keys + per-block bucket histogram (LDS atomics only)
__global__ __launch_bounds__(256) void sort_hist_kernel(const int* __restrict__ src,
                                                        const int* __restrict__ dst,
                                                        uint* __restrict__ key,
                                                        int* __restrict__ gh, int n) {
    __shared__ int h[NBUCK];
    int blk = blockIdx.x;
    for (int i = threadIdx.x; i < NBUCK; i += 256) h[i] = 0;
    __syncthreads();
    int base = blk * CHUNK;
    int end = base + CHUNK < n ? base + CHUNK : n;
    for (int i = base + threadIdx.x; i < end; i += 256) {
        int d = dst[i];
        key[i] = ((uint)d << 16) | (uint)src[i];
        atomicAdd(&h[d >> 8], 1);
    }
    __syncthreads();
    for (int i = threadIdx.x; i < NBUCK; i += 256) gh[blk * NBUCK + i] = h[i];
}

// S2: per-(block,bucket) exclusive offsets + bucket bases (single block)
__global__ __launch_bounds__(256) void sort_offsets_kernel(const int* __restrict__ gh,
                                                           int* __restrict__ offraw,
                                                           int* __restrict__ bbase) {
    __shared__ int tot[NBUCK];
    int b = threadIdx.x;
    if (b < NBUCK) {
        int run = 0;
        for (int blk = 0; blk < NB1; blk++) {
            offraw[blk * NBUCK + b] = run;
            run += gh[blk * NBUCK + b];
        }
        tot[b] = run;
    }
    __syncthreads();
    if (threadIdx.x == 0) {
        int run = 0;
        for (int i = 0; i < NBUCK; i++) { bbase[i] = run; run += tot[i]; }
        bbase[NBUCK] = run;   // == NEDGES
    }
}

// S3: partition into 196 coarse buckets; each block writes only its own runs
__global__ __launch_bounds__(256) void sort_scatter1_kernel(const uint* __restrict__ key,
                                                            const int* __restrict__ offraw,
                                                            const int* __restrict__ bbase,
                                                            uint* __restrict__ out, int n) {
    __shared__ int cur[NBUCK];
    int blk = blockIdx.x;
    for (int i = threadIdx.x; i < NBUCK; i += 256)
        cur[i] = bbase[i] + offraw[blk * NBUCK + i];
    __syncthreads();
    int base = blk * CHUNK;
    int end = base + CHUNK < n ? base + CHUNK : n;
    for (int i = base + threadIdx.x; i < end; i += 256) {
        uint k = key[i];
        int pos = atomicAdd(&cur[k >> 24], 1);   // k>>24 == dst>>8
        out[pos] = k;
    }
}

// S4: per-bucket counting sort by dst&255 -> final dst-grouped edge array
__global__ __launch_bounds__(256) void sort_bucket_kernel(const uint* __restrict__ in,
                                                          const int* __restrict__ bbase,
                                                          uint* __restrict__ out) {
    __shared__ int h[256];
    __shared__ int cur[256];
    int b = blockIdx.x;
    int lo = bbase[b], hi = bbase[b + 1];
    h[threadIdx.x] = 0;
    __syncthreads();
    for (int i = lo + threadIdx.x; i < hi; i += 256)
        atomicAdd(&h[(in[i] >> 16) & 255], 1);
    __syncthreads();
    if (threadIdx.x == 0) {
        int run = lo;
        for (int i = 0; i < 256; i++) { cur[i] = run; run += h[i]; }
    }
    __syncthreads();
    for (int i = lo + threadIdx.x; i < hi; i += 256) {
        uint k = in[i];
        int pos = atomicAdd(&cur[(k >> 16) & 255], 1);
        out[pos] = k;
    }
}

// S5: rowptr from boundaries of the sorted key array
__global__ __launch_bounds__(256) void rowptr_kernel(const uint* __restrict__ skey,
                                                     int* __restrict__ rowptr, int ne) {
    int i = blockIdx.x * 256 + threadIdx.x;
    if (i >= ne) return;
    int d = (int)(skey[i] >> 16);
    int dprev = (i == 0) ? -1 : (int)(skey[i - 1] >> 16);
    for (int v = dprev + 1; v <= d; v++) rowptr[v] = i;
    if (i == ne - 1)
        for (int v = d + 1; v <= NNODES; v++) rowptr[v] = ne;
}

// ---------------- features fp32 -> bf16 ----------------

__global__ void cvt_kernel(const float2* __restrict__ in, uint* __restrict__ out, int n2) {
    int i = blockIdx.x * 256 + threadIdx.x;
    if (i < n2) {
        float2 v = in[i];
        out[i] = f2bf(v.x) | (f2bf(v.y) << 16);
    }
}

// ---------------- aggregation (bf16): r[n] = h[n] + sum_{e in(n)} h[src[e]] ----------------
// quarter-wave per node: 16 lanes x uint2 (4 dims each). Edge unroll 8 for MLW.
// csr entries are packed keys; src = key & 0xffff.

__global__ __launch_bounds__(256) void agg_kernel(const uint2* __restrict__ h64,
                                                  const int* __restrict__ rowptr,
                                                  const uint* __restrict__ csr,
                                                  uint2* __restrict__ r64, int n) {
    int idx = blockIdx.x * 256 + threadIdx.x;
    int node = idx >> 4;
    int p = idx & 15;
    if (node >= n) return;
    uint2 u = h64[(size_t)node * 16 + p];
    float a0 = bf_lo(u.x), a1 = bf_hi(u.x), a2 = bf_lo(u.y), a3 = bf_hi(u.y);
    int e = rowptr[node], end = rowptr[node + 1];
    for (; e + 7 < end; e += 8) {
        uint2 v0 = h64[(size_t)(csr[e + 0] & 0xffffu) * 16 + p];
        uint2 v1 = h64[(size_t)(csr[e + 1] & 0xffffu) * 16 + p];
        uint2 v2 = h64[(size_t)(csr[e + 2] & 0xffffu) * 16 + p];
        uint2 v3 = h64[(size_t)(csr[e + 3] & 0xffffu) * 16 + p];
        uint2 v4 = h64[(size_t)(csr[e + 4] & 0xffffu) * 16 + p];
        uint2 v5 = h64[(size_t)(csr[e + 5] & 0xffffu) * 16 + p];
        uint2 v6 = h64[(size_t)(csr[e + 6] & 0xffffu) * 16 + p];
        uint2 v7 = h64[(size_t)(csr[e + 7] & 0xffffu) * 16 + p];
        a0 += bf_lo(v0.x); a1 += bf_hi(v0.x); a2 += bf_lo(v0.y); a3 += bf_hi(v0.y);
        a0 += bf_lo(v1.x); a1 += bf_hi(v1.x); a2 += bf_lo(v1.y); a3 += bf_hi(v1.y);
        a0 += bf_lo(v2.x); a1 += bf_hi(v2.x); a2 += bf_lo(v2.y); a3 += bf_hi(v2.y);
        a0 += bf_lo(v3.x); a1 += bf_hi(v3.x); a2 += bf_lo(v3.y); a3 += bf_hi(v3.y);
        a0 += bf_lo(v4.x); a1 += bf_hi(v4.x); a2 += bf_lo(v4.y); a3 += bf_hi(v4.y);
        a0 += bf_lo(v5.x); a1 += bf_hi(v5.x); a2 += bf_lo(v5.y); a3 += bf_hi(v5.y);
        a0 += bf_lo(v6.x); a1 += bf_hi(v6.x); a2 += bf_lo(v6.y); a3 += bf_hi(v6.y);
        a0 += bf_lo(v7.x); a1 += bf_hi(v7.x); a2 += bf_lo(v7.y); a3 += bf_hi(v7.y);
    }
    for (; e < end; e++) {
        uint2 v0 = h64[(size_t)(csr[e] & 0xffffu) * 16 + p];
        a0 += bf_lo(v0.x); a1 += bf_hi(v0.x); a2 += bf_lo(v0.y); a3 += bf_hi(v0.y);
    }
    r64[(size_t)node * 16 + p] =
        make_uint2(f2bf(a0) | (f2bf(a1) << 16), f2bf(a2) | (f2bf(a3) << 16));
}

// ---------------- MLP: out = relu(r@Wa+ba)@Wb+bb  (bf16 in/out) ----------------

__global__ __launch_bounds__(256) void mlp_kernel(const uint2* __restrict__ r64,
                                                  const float* __restrict__ Wa,
                                                  const float* __restrict__ ba,
                                                  const float* __restrict__ Wb,
                                                  const float* __restrict__ bb,
                                                  uint2* __restrict__ out64, int n) {
    __shared__ float sA[64][64];   // Wa[k][j]
    __shared__ float sB[64][64];   // Wb[k][j]
    __shared__ float sR[64][65];   // input tile, reused as hidden tile
    __shared__ float sba[64], sbb[64];

    int t = threadIdx.x;
    for (int i = t; i < 1024; i += 256) {
        ((float4*)sA)[i] = ((const float4*)Wa)[i];
        ((float4*)sB)[i] = ((const float4*)Wb)[i];
    }
    if (t < 64) { sba[t] = ba[t]; sbb[t] = bb[t]; }

    int node0 = blockIdx.x * 64;
    for (int i = t; i < 1024; i += 256) {
        int row = i >> 4;       // 0..63
        int q   = i & 15;       // uint2 index within row
        int gr = node0 + row;
        uint2 v = make_uint2(0u, 0u);
        if (gr < n) v = r64[(size_t)gr * 16 + q];
        sR[row][4 * q + 0] = bf_lo(v.x);
        sR[row][4 * q + 1] = bf_hi(v.x);
        sR[row][4 * q + 2] = bf_lo(v.y);
        sR[row][4 * q + 3] = bf_hi(v.y);
    }
    __syncthreads();

    int tx = t & 15;            // output-col group: j0 = tx*4
    int ty = t >> 4;            // node-row group:  i0 = ty*4
    int j0 = tx * 4, i0 = ty * 4;

    float acc[4][4];
#pragma unroll
    for (int a = 0; a < 4; a++)
#pragma unroll
        for (int b = 0; b < 4; b++) acc[a][b] = 0.f;

#pragma unroll 8
    for (int k = 0; k < 64; k++) {
        float a0 = sR[i0 + 0][k];
        float a1 = sR[i0 + 1][k];
        float a2 = sR[i0 + 2][k];
        float a3 = sR[i0 + 3][k];
        float4 bv = *(const float4*)&sA[k][j0];
        acc[0][0] += a0 * bv.x; acc[0][1] += a0 * bv.y; acc[0][2] += a0 * bv.z; acc[0][3] += a0 * bv.w;
        acc[1][0] += a1 * bv.x; acc[1][1] += a1 * bv.y; acc[1][2] += a1 * bv.z; acc[1][3] += a1 * bv.w;
        acc[2][0] += a2 * bv.x; acc[2][1] += a2 * bv.y; acc[2][2] += a2 * bv.z; acc[2][3] += a2 * bv.w;
        acc[3][0] += a3 * bv.x; acc[3][1] += a3 * bv.y; acc[3][2] += a3 * bv.z; acc[3][3] += a3 * bv.w;
    }
    __syncthreads();   // all reads of sR done before overwrite

#pragma unroll
    for (int a = 0; a < 4; a++)
#pragma unroll
        for (int b = 0; b < 4; b++)
            sR[i0 + a][j0 + b] = fmaxf(acc[a][b] + sba[j0 + b], 0.f);
    __syncthreads();

#pragma unroll
    for (int a = 0; a < 4; a++)
#pragma unroll
        for (int b = 0; b < 4; b++) acc[a][b] = 0.f;

#pragma unroll 8
    for (int k = 0; k < 64; k++) {
        float a0 = sR[i0 + 0][k];
        float a1 = sR[i0 + 1][k];
        float a2 = sR[i0 + 2][k];
        float a3 = sR[i0 + 3][k];
        float4 bv = *(const float4*)&sB[k][j0];
        acc[0][0] += a0 * bv.x; acc[0][1] += a0 * bv.y; acc[0][2] += a0 * bv.z; acc[0][3] += a0 * bv.w;
        acc[1][0] += a1 * bv.x; acc[1][1] += a1 * bv.y; acc[1][2] += a1 * bv.z; acc[1][3] += a1 * bv.w;
        acc[2][0] += a2 * bv.x; acc[2][1] += a2 * bv.y; acc[2][2] += a2 * bv.z; acc[2][3] += a2 * bv.w;
        acc[3][0] += a3 * bv.x; acc[3][1] += a3 * bv.y; acc[3][2] += a3 * bv.z; acc[3][3] += a3 * bv.w;
    }

#pragma unroll
    for (int a = 0; a < 4; a++) {
        int gr = node0 + i0 + a;
        if (gr < n) {
            uint q0 = f2bf(acc[a][0] + sbb[j0 + 0]) | (f2bf(acc[a][1] + sbb[j0 + 1]) << 16);
            uint q1 = f2bf(acc[a][2] + sbb[j0 + 2]) | (f2bf(acc[a][3] + sbb[j0 + 3]) << 16);
            out64[(size_t)gr * 16 + tx] = make_uint2(q0, q1);
        }
    }
}

// ---------------- mean pool (2 stages, bf16 input) + final linear ----------------

__global__ __launch_bounds__(256) void colsum_part_kernel(const uint* __restrict__ h32,
                                                          float* __restrict__ part, int n) {
    __shared__ float red[8][64];
    int t = threadIdx.x;
    int g = t >> 5, p = t & 31;
    float a0 = 0.f, a1 = 0.f;
    for (int i = blockIdx.x * 8 + g; i < n; i += gridDim.x * 8) {
        uint u = h32[(size_t)i * 32 + p];
        a0 += bf_lo(u);
        a1 += bf_hi(u);
    }
    red[g][2 * p]     = a0;
    red[g][2 * p + 1] = a1;
    __syncthreads();
    if (t < 64) {
        float s = 0.f;
        for (int gg = 0; gg < 8; gg++) s += red[gg][t];
        part[blockIdx.x * 64 + t] = s;
    }
}

__global__ __launch_bounds__(64) void final_kernel(const float* __restrict__ part,
                                                   const float* __restrict__ Wout,
                                                   const float* __restrict__ bout,
                                                   float* __restrict__ out, int nparts) {
    __shared__ float cs[64];
    int t = threadIdx.x;
    float s = 0.f;
    for (int b = 0; b < nparts; b++) s += part[b * 64 + t];
    cs[t] = s * (1.0f / (float)NNODES);
    __syncthreads();
    if (t < DOUT) {
        float o = bout[t];
        for (int d = 0; d < DDIM; d++) o += cs[d] * Wout[d * DOUT + t];
        out[t] = o;
    }
}

// ---------------- launch ----------------

extern "C" void kernel_launch(void* const* d_in, const int* in_sizes, int n_in,
                              void* d_out, int out_size, void* d_ws, size_t ws_size,
                              hipStream_t stream) {
    const float* features = (const float*)d_in[0];
    const int*   src      = (const int*)d_in[1];
    const int*   dst      = (const int*)d_in[2];
    const float* W0a = (const float*)d_in[3];  const float* b0a = (const float*)d_in[4];
    const float* W0b = (const float*)d_in[5];  const float* b0b = (const float*)d_in[6];
    const float* W1a = (const float*)d_in[7];  const float* b1a = (const float*)d_in[8];
    const float* W1b = (const float*)d_in[9];  const float* b1b = (const float*)d_in[10];
    const float* W2a = (const float*)d_in[11]; const float* b2a = (const float*)d_in[12];
    const float* W2b = (const float*)d_in[13]; const float* b2b = (const float*)d_in[14];
    const float* Wout = (const float*)d_in[15]; const float* bout = (const float*)d_in[16];
    float* out = (float*)d_out;

    // workspace layout (16B-aligned segments)
    int* gh     = (int*)d_ws;              // [38416] -> pad 38416
    int* offraw = gh + 38416;              // [38416]
    int* bbase  = offraw + 38416;          // [197] -> pad 208
    int* rowptr = bbase + 208;             // [50001] -> pad 50016
    uint* keybuf = (uint*)(rowptr + 50016);  // [800000] (also final sorted = csr)
    uint* buf2   = keybuf + 800000;          // [800000] (pass-1 partitioned)
    uint* hb0    = buf2 + 800000;            // bf16 h ping [50000*32]
    uint* hb1    = hb0 + NNODES * 32;        // bf16 h pong
    uint* rb     = hb1 + NNODES * 32;        // bf16 r buffer
    float* part  = (float*)(rb + NNODES * 32); // [128*64]

    // edge sort -> dst-grouped packed keys in keybuf, rowptr
    sort_hist_kernel<<<NB1, 256, 0, stream>>>(src, dst, keybuf, gh, NEDGES);
    sort_offsets_kernel<<<1, 256, 0, stream>>>(gh, offraw, bbase);
    sort_scatter1_kernel<<<NB1, 256, 0, stream>>>(keybuf, offraw, bbase, buf2, NEDGES);
    sort_bucket_kernel<<<NBUCK, 256, 0, stream>>>(buf2, bbase, keybuf);
    rowptr_kernel<<<(NEDGES + 255) / 256, 256, 0, stream>>>(keybuf, rowptr, NEDGES);

    // features -> bf16
    cvt_kernel<<<(NNODES * 32 + 255) / 256, 256, 0, stream>>>((const float2*)features, hb0, NNODES * 32);

    const int AGG_BLOCKS = (NNODES * 16 + 255) / 256;  // 3125 (16 lanes/node)
    const int MLP_BLOCKS = (NNODES + 63) / 64;         // 782

    // layer 0
    agg_kernel<<<AGG_BLOCKS, 256, 0, stream>>>((const uint2*)hb0, rowptr, keybuf, (uint2*)rb, NNODES);
    mlp_kernel<<<MLP_BLOCKS, 256, 0, stream>>>((const uint2*)rb, W0a, b0a, W0b, b0b, (uint2*)hb1, NNODES);
    // layer 1
    agg_kernel<<<AGG_BLOCKS, 256, 0, stream>>>((const uint2*)hb1, rowptr, keybuf, (uint2*)rb, NNODES);
    mlp_kernel<<<MLP_BLOCKS, 256, 0, stream>>>((const uint2*)rb, W1a, b1a, W1b, b1b, (uint2*)hb0, NNODES);
    // layer 2
    agg_kernel<<<AGG_BLOCKS, 256, 0, stream>>>((const uint2*)hb0, rowptr, keybuf, (uint2*)rb, NNODES);
    mlp_kernel<<<MLP_BLOCKS, 256, 0, stream>>>((const uint2*)rb, W2a, b2a, W2b, b2b, (uint2*)hb1, NNODES);

    // mean pool + final linear
    colsum_part_kernel<<<128, 256, 0, stream>>>(hb1, part, NNODES);
    final_kernel<<<1, 64, 0, stream>>>(part, Wout, bout, out, 128);
}

// Round 6
// 286.902 us; speedup vs baseline: 1.8068x; 1.0945x over previous
//
#include <hip/hip_runtime.h>
#include <hip/hip_bf16.h>

// GIN: 3x [agg = segment_sum(h[src], dst); r = h + agg; h = relu(r@Wa+ba)@Wb+bb]
// then mean over nodes @ Wout + bout -> [1,16]
//
// R6: (a) agg gather software-pipelined: csr indices for chunk i+1 prefetched
// while chunk i's rows are gathered (breaks the idx->gather 2-latency chain).
// (b) MLP rewritten on MFMA bf16 16x16x32: wave-private 16-row blocks, only 2
// barriers, weights transposed to LDS for contiguous B-fragments.
// CSR build = R5's no-global-atomic MSD bucket sort (keys dst<<16|src).

#define NNODES 50000
#define NEDGES 800000
#define DDIM   64
#define DOUT   16

#define CHUNK  4096
#define NB1    196           // ceil(800000/4096)
#define NBUCK  196           // ceil(50000/256), bucket = dst>>8

typedef unsigned int uint;
typedef unsigned short ushort;
typedef __attribute__((ext_vector_type(8))) short bf16x8;
typedef __attribute__((ext_vector_type(4))) float f32x4;

#define LSTR 88   // LDS row stride in ushorts: 176B = 16B-aligned, 12-bank shift -> 2-way max on b128

// fp32 -> bf16 RNE (bit trick)
static __device__ __forceinline__ uint f2bf(float f) {
    uint u = __float_as_uint(f);
    return (u + 0x7fffu + ((u >> 16) & 1u)) >> 16;
}
static __device__ __forceinline__ float bf_lo(uint u) { return __uint_as_float(u << 16); }
static __device__ __forceinline__ float bf_hi(uint u) { return __uint_as_float(u & 0xffff0000u); }

// ---------------- edge sort (2-pass MSD bucket sort, no global atomics) ----------------

__global__ __launch_bounds__(256) void sort_hist_kernel(const int* __restrict__ src,
                                                        const int* __restrict__ dst,
                                                        uint* __restrict__ key,
                                                        int* __restrict__ gh, int n) {
    __shared__ int h[NBUCK];
    int blk = blockIdx.x;
    for (int i = threadIdx.x; i < NBUCK; i += 256) h[i] = 0;
    __syncthreads();
    int base = blk * CHUNK;
    int end = base + CHUNK < n ? base + CHUNK : n;
    for (int i = base + threadIdx.x; i < end; i += 256) {
        int d = dst[i];
        key[i] = ((uint)d << 16) | (uint)src[i];
        atomicAdd(&h[d >> 8], 1);
    }
    __syncthreads();
    for (int i = threadIdx.x; i < NBUCK; i += 256) gh[blk * NBUCK + i] = h[i];
}

__global__ __launch_bounds__(256) void sort_offsets_kernel(const int* __restrict__ gh,
                                                           int* __restrict__ offraw,
                                                           int* __restrict__ bbase) {
    __shared__ int tot[NBUCK];
    int b = threadIdx.x;
    if (b < NBUCK) {
        int run = 0;
        for (int blk = 0; blk < NB1; blk++) {
            offraw[blk * NBUCK + b] = run;
            run += gh[blk * NBUCK + b];
        }
        tot[b] = run;
    }
    __syncthreads();
    if (threadIdx.x == 0) {
        int run = 0;
        for (int i = 0; i < NBUCK; i++) { bbase[i] = run; run += tot[i]; }
        bbase[NBUCK] = run;   // == NEDGES
    }
}

__global__ __launch_bounds__(256) void sort_scatter1_kernel(const uint* __restrict__ key,
                                                            const int* __restrict__ offraw,
                                                            const int* __restrict__ bbase,
                                                            uint* __restrict__ out, int n) {
    __shared__ int cur[NBUCK];
    int blk = blockIdx.x;
    for (int i = threadIdx.x; i < NBUCK; i += 256)
        cur[i] = bbase[i] + offraw[blk * NBUCK + i];
    __syncthreads();
    int base = blk * CHUNK;
    int end = base + CHUNK < n ? base + CHUNK : n;
    for (int i = base + threadIdx.x; i < end; i += 256) {
        uint k = key[i];
        int pos = atomicAdd(&cur[k >> 24], 1);   // k>>24 == dst>>8
        out[pos] = k;
    }
}

__global__ __launch_bounds__(256) void sort_bucket_kernel(const uint* __restrict__ in,
                                                          const int* __restrict__ bbase,
                                                          uint* __restrict__ out) {
    __shared__ int h[256];
    __shared__ int cur[256];
    int b = blockIdx.x;
    int lo = bbase[b], hi = bbase[b + 1];
    h[threadIdx.x] = 0;
    __syncthreads();
    for (int i = lo + threadIdx.x; i < hi; i += 256)
        atomicAdd(&h[(in[i] >> 16) & 255], 1);
    __syncthreads();
    if (threadIdx.x == 0) {
        int run = lo;
        for (int i = 0; i < 256; i++) { cur[i] = run; run += h[i]; }
    }
    __syncthreads();
    for (int i = lo + threadIdx.x; i < hi; i += 256) {
        uint k = in[i];
        int pos = atomicAdd(&cur[(k >> 16) & 255], 1);
        out[pos] = k;
    }
}

__global__ __launch_bounds__(256) void rowptr_kernel(const uint* __restrict__ skey,
                                                     int* __restrict__ rowptr, int ne) {
    int i = blockIdx.x * 256 + threadIdx.x;
    if (i >= ne) return;
    int d = (int)(skey[i] >> 16);
    int dprev = (i == 0) ? -1 : (int)(skey[i - 1] >> 16);
    for (int v = dprev + 1; v <= d; v++) rowptr[v] = i;
    if (i == ne - 1)
        for (int v = d + 1; v <= NNODES; v++) rowptr[v] = ne;
}

// ---------------- features fp32 -> bf16 ----------------

__global__ void cvt_kernel(const float2* __restrict__ in, uint* __restrict__ out, int n2) {
    int i = blockIdx.x * 256 + threadIdx.x;
    if (i < n2) {
        float2 v = in[i];
        out[i] = f2bf(v.x) | (f2bf(v.y) << 16);
    }
}

// ---------------- aggregation (bf16): r[n] = h[n] + sum_{e in(n)} h[src[e]] ----------------
// quarter-wave per node: 16 lanes x uint2 (4 dims each). Chunk 8, index
// prefetch one chunk ahead so gathers of chunk i overlap csr loads of i+1.

__global__ __launch_bounds__(256) void agg_kernel(const uint2* __restrict__ h64,
                                                  const int* __restrict__ rowptr,
                                                  const uint* __restrict__ csr,
                                                  uint2* __restrict__ r64, int n) {
    int idx = blockIdx.x * 256 + threadIdx.x;
    int node = idx >> 4;
    int p = idx & 15;
    if (node >= n) return;
    uint2 u = h64[(size_t)node * 16 + p];
    float a0 = bf_lo(u.x), a1 = bf_hi(u.x), a2 = bf_lo(u.y), a3 = bf_hi(u.y);
    int e = rowptr[node], end = rowptr[node + 1];
    int i0 = 0, i1 = 0, i2 = 0, i3 = 0, i4 = 0, i5 = 0, i6 = 0, i7 = 0;
    if (e + 8 <= end) {
        i0 = csr[e + 0] & 0xffff; i1 = csr[e + 1] & 0xffff;
        i2 = csr[e + 2] & 0xffff; i3 = csr[e + 3] & 0xffff;
        i4 = csr[e + 4] & 0xffff; i5 = csr[e + 5] & 0xffff;
        i6 = csr[e + 6] & 0xffff; i7 = csr[e + 7] & 0xffff;
    }
    while (e + 8 <= end) {
        int c0 = i0, c1 = i1, c2 = i2, c3 = i3, c4 = i4, c5 = i5, c6 = i6, c7 = i7;
        int en = e + 8;
        if (en + 8 <= end) {   // prefetch next chunk's indices (uniform per quarter)
            i0 = csr[en + 0] & 0xffff; i1 = csr[en + 1] & 0xffff;
            i2 = csr[en + 2] & 0xffff; i3 = csr[en + 3] & 0xffff;
            i4 = csr[en + 4] & 0xffff; i5 = csr[en + 5] & 0xffff;
            i6 = csr[en + 6] & 0xffff; i7 = csr[en + 7] & 0xffff;
        }
        uint2 v0 = h64[(size_t)c0 * 16 + p];
        uint2 v1 = h64[(size_t)c1 * 16 + p];
        uint2 v2 = h64[(size_t)c2 * 16 + p];
        uint2 v3 = h64[(size_t)c3 * 16 + p];
        uint2 v4 = h64[(size_t)c4 * 16 + p];
        uint2 v5 = h64[(size_t)c5 * 16 + p];
        uint2 v6 = h64[(size_t)c6 * 16 + p];
        uint2 v7 = h64[(size_t)c7 * 16 + p];
        a0 += bf_lo(v0.x); a1 += bf_hi(v0.x); a2 += bf_lo(v0.y); a3 += bf_hi(v0.y);
        a0 += bf_lo(v1.x); a1 += bf_hi(v1.x); a2 += bf_lo(v1.y); a3 += bf_hi(v1.y);
        a0 += bf_lo(v2.x); a1 += bf_hi(v2.x); a2 += bf_lo(v2.y); a3 += bf_hi(v2.y);
        a0 += bf_lo(v3.x); a1 += bf_hi(v3.x); a2 += bf_lo(v3.y); a3 += bf_hi(v3.y);
        a0 += bf_lo(v4.x); a1 += bf_hi(v4.x); a2 += bf_lo(v4.y); a3 += bf_hi(v4.y);
        a0 += bf_lo(v5.x); a1 += bf_hi(v5.x); a2 += bf_lo(v5.y); a3 += bf_hi(v5.y);
        a0 += bf_lo(v6.x); a1 += bf_hi(v6.x); a2 += bf_lo(v6.y); a3 += bf_hi(v6.y);
        a0 += bf_lo(v7.x); a1 += bf_hi(v7.x); a2 += bf_lo(v7.y); a3 += bf_hi(v7.y);
        e = en;
    }
    for (; e < end; e++) {
        uint2 v0 = h64[(size_t)(csr[e] & 0xffffu) * 16 + p];
        a0 += bf_lo(v0.x); a1 += bf_hi(v0.x); a2 += bf_lo(v0.y); a3 += bf_hi(v0.y);
    }
    r64[(size_t)node * 16 + p] =
        make_uint2(f2bf(a0) | (f2bf(a1) << 16), f2bf(a2) | (f2bf(a3) << 16));
}

// ---------------- MLP via MFMA: out = relu(r@Wa+ba)@Wb+bb  (bf16 in/out) ----------------
// 64 nodes/block, 4 waves; wave w owns rows [w*16, w*16+16).
// A-frag: A[m=lane&15][k=quad*8+j]; B-frag: B[k=quad*8+j][n=lane&15] (weights
// staged TRANSPOSED so B-frag is one contiguous 16B LDS read);
// D: col=lane&15, row=quad*4+reg (verified layouts, learn_hip m89/m91/m118).

__global__ __launch_bounds__(256) void mlp_kernel(const uint2* __restrict__ r64,
                                                  const float* __restrict__ Wa,
                                                  const float* __restrict__ ba,
                                                  const float* __restrict__ Wb,
                                                  const float* __restrict__ bb,
                                                  uint2* __restrict__ out64, int n) {
    __shared__ ushort sW1[64 * LSTR];   // Wa^T: [n][k]
    __shared__ ushort sW2[64 * LSTR];   // Wb^T: [n][k]
    __shared__ ushort sX[64 * LSTR];    // input rows [m][k]; reused as output staging
    __shared__ ushort sH[64 * LSTR];    // hidden rows [m][k]
    __shared__ float sba[64], sbb[64];

    int t = threadIdx.x;
    for (int i = t; i < 4096; i += 256) {
        int k = i >> 6, nn = i & 63;           // coalesced read of W[k][n]
        sW1[nn * LSTR + k] = (ushort)f2bf(Wa[i]);
        sW2[nn * LSTR + k] = (ushort)f2bf(Wb[i]);
    }
    if (t < 64) { sba[t] = ba[t]; sbb[t] = bb[t]; }

    int node0 = blockIdx.x * 64;
    for (int i = t; i < 1024; i += 256) {
        int row = i >> 4, q = i & 15;
        uint2 v = make_uint2(0u, 0u);
        int gr = node0 + row;
        if (gr < n) v = r64[(size_t)gr * 16 + q];
        *(uint2*)&sX[row * LSTR + q * 4] = v;  // rows are already [m][k] bf16
    }
    __syncthreads();

    int lane = t & 63;
    int w = t >> 6;            // wave id 0..3
    int m0 = w * 16;
    int mc = lane & 15;
    int quad = lane >> 4;

    // ---- matmul 1: H = relu(X @ Wa + ba)  (wave-private rows, no barrier)
    bf16x8 xa0 = *(const bf16x8*)&sX[(m0 + mc) * LSTR + quad * 8];
    bf16x8 xa1 = *(const bf16x8*)&sX[(m0 + mc) * LSTR + 32 + quad * 8];
#pragma unroll
    for (int c = 0; c < 4; c++) {
        bf16x8 b0 = *(const bf16x8*)&sW1[(c * 16 + mc) * LSTR + quad * 8];
        bf16x8 b1 = *(const bf16x8*)&sW1[(c * 16 + mc) * LSTR + 32 + quad * 8];
        f32x4 acc = {0.f, 0.f, 0.f, 0.f};
        acc = __builtin_amdgcn_mfma_f32_16x16x32_bf16(xa0, b0, acc, 0, 0, 0);
        acc = __builtin_amdgcn_mfma_f32_16x16x32_bf16(xa1, b1, acc, 0, 0, 0);
        int col = c * 16 + mc;
        float bias = sba[col];
#pragma unroll
        for (int r = 0; r < 4; r++) {
            int row = m0 + quad * 4 + r;
            sH[row * LSTR + col] = (ushort)f2bf(fmaxf(acc[r] + bias, 0.f));
        }
    }

    // ---- matmul 2: O = H @ Wb + bb (still wave-private; compiler inserts lgkm waits)
    bf16x8 ha0 = *(const bf16x8*)&sH[(m0 + mc) * LSTR + quad * 8];
    bf16x8 ha1 = *(const bf16x8*)&sH[(m0 + mc) * LSTR + 32 + quad * 8];
#pragma unroll
    for (int c = 0; c < 4; c++) {
        bf16x8 b0 = *(const bf16x8*)&sW2[(c * 16 + mc) * LSTR + quad * 8];
        bf16x8 b1 = *(const bf16x8*)&sW2[(c * 16 + mc) * LSTR + 32 + quad * 8];
        f32x4 acc = {0.f, 0.f, 0.f, 0.f};
        acc = __builtin_amdgcn_mfma_f32_16x16x32_bf16(ha0, b0, acc, 0, 0, 0);
        acc = __builtin_amdgcn_mfma_f32_16x16x32_bf16(ha1, b1, acc, 0, 0, 0);
        int col = c * 16 + mc;
        float bias = sbb[col];
#pragma unroll
        for (int r = 0; r < 4; r++) {
            int row = m0 + quad * 4 + r;
            sX[row * LSTR + col] = (ushort)f2bf(acc[r] + bias);  // reuse sX as staging
        }
    }
    __syncthreads();

    for (int i = t; i < 1024; i += 256) {
        int row = i >> 4, q = i & 15;
        int gr = node0 + row;
        if (gr < n) out64[(size_t)gr * 16 + q] = *(uint2*)&sX[row * LSTR + q * 4];
    }
}

// ---------------- mean pool (2 stages, bf16 input) + final linear ----------------

__global__ __launch_bounds__(256) void colsum_part_kernel(const uint* __restrict__ h32,
                                                          float* __restrict__ part, int n) {
    __shared__ float red[8][64];
    int t = threadIdx.x;
    int g = t >> 5, p = t & 31;
    float a0 = 0.f, a1 = 0.f;
    for (int i = blockIdx.x * 8 + g; i < n; i += gridDim.x * 8) {
        uint u = h32[(size_t)i * 32 + p];
        a0 += bf_lo(u);
        a1 += bf_hi(u);
    }
    red[g][2 * p]     = a0;
    red[g][2 * p + 1] = a1;
    __syncthreads();
    if (t < 64) {
        float s = 0.f;
        for (int gg = 0; gg < 8; gg++) s += red[gg][t];
        part[blockIdx.x * 64 + t] = s;
    }
}

__global__ __launch_bounds__(64) void final_kernel(const float* __restrict__ part,
                                                   const float* __restrict__ Wout,
                                                   const float* __restrict__ bout,
                                                   float* __restrict__ out, int nparts) {
    __shared__ float cs[64];
    int t = threadIdx.x;
    float s = 0.f;
    for (int b = 0; b < nparts; b++) s += part[b * 64 + t];
    cs[t] = s * (1.0f / (float)NNODES);
    __syncthreads();
    if (t < DOUT) {
        float o = bout[t];
        for (int d = 0; d < DDIM; d++) o += cs[d] * Wout[d * DOUT + t];
        out[t] = o;
    }
}

// ---------------- launch ----------------

extern "C" void kernel_launch(void* const* d_in, const int* in_sizes, int n_in,
                              void* d_out, int out_size, void* d_ws, size_t ws_size,
                              hipStream_t stream) {
    const float* features = (const float*)d_in[0];
    const int*   src      = (const int*)d_in[1];
    const int*   dst      = (const int*)d_in[2];
    const float* W0a = (const float*)d_in[3];  const float* b0a = (const float*)d_in[4];
    const float* W0b = (const float*)d_in[5];  const float* b0b = (const float*)d_in[6];
    const float* W1a = (const float*)d_in[7];  const float* b1a = (const float*)d_in[8];
    const float* W1b = (const float*)d_in[9];  const float* b1b = (const float*)d_in[10];
    const float* W2a = (const float*)d_in[11]; const float* b2a = (const float*)d_in[12];
    const float* W2b = (const float*)d_in[13]; const float* b2b = (const float*)d_in[14];
    const float* Wout = (const float*)d_in[15]; const float* bout = (const float*)d_in[16];
    float* out = (float*)d_out;

    // workspace layout (16B-aligned segments)
    int* gh     = (int*)d_ws;              // [38416]
    int* offraw = gh + 38416;              // [38416]
    int* bbase  = offraw + 38416;          // [197] -> pad 208
    int* rowptr = bbase + 208;             // [50001] -> pad 50016
    uint* keybuf = (uint*)(rowptr + 50016);  // [800000] (final sorted = csr)
    uint* buf2   = keybuf + 800000;          // [800000] (pass-1 partitioned)
    uint* hb0    = buf2 + 800000;            // bf16 h ping [50000*32]
    uint* hb1    = hb0 + NNODES * 32;        // bf16 h pong
    uint* rb     = hb1 + NNODES * 32;        // bf16 r buffer
    float* part  = (float*)(rb + NNODES * 32); // [128*64]

    // edge sort -> dst-grouped packed keys in keybuf, rowptr
    sort_hist_kernel<<<NB1, 256, 0, stream>>>(src, dst, keybuf, gh, NEDGES);
    sort_offsets_kernel<<<1, 256, 0, stream>>>(gh, offraw, bbase);
    sort_scatter1_kernel<<<NB1, 256, 0, stream>>>(keybuf, offraw, bbase, buf2, NEDGES);
    sort_bucket_kernel<<<NBUCK, 256, 0, stream>>>(buf2, bbase, keybuf);
    rowptr_kernel<<<(NEDGES + 255) / 256, 256, 0, stream>>>(keybuf, rowptr, NEDGES);

    // features -> bf16
    cvt_kernel<<<(NNODES * 32 + 255) / 256, 256, 0, stream>>>((const float2*)features, hb0, NNODES * 32);

    const int AGG_BLOCKS = (NNODES * 16 + 255) / 256;  // 3125 (16 lanes/node)
    const int MLP_BLOCKS = (NNODES + 63) / 64;         // 782

    // layer 0
    agg_kernel<<<AGG_BLOCKS, 256, 0, stream>>>((const uint2*)hb0, rowptr, keybuf, (uint2*)rb, NNODES);
    mlp_kernel<<<MLP_BLOCKS, 256, 0, stream>>>((const uint2*)rb, W0a, b0a, W0b, b0b, (uint2*)hb1, NNODES);
    // layer 1
    agg_kernel<<<AGG_BLOCKS, 256, 0, stream>>>((const uint2*)hb1, rowptr, keybuf, (uint2*)rb, NNODES);
    mlp_kernel<<<MLP_BLOCKS, 256, 0, stream>>>((const uint2*)rb, W1a, b1a, W1b, b1b, (uint2*)hb0, NNODES);
    // layer 2
    agg_kernel<<<AGG_BLOCKS, 256, 0, stream>>>((const uint2*)hb0, rowptr, keybuf, (uint2*)rb, NNODES);
    mlp_kernel<<<MLP_BLOCKS, 256, 0, stream>>>((const uint2*)rb, W2a, b2a, W2b, b2b, (uint2*)hb1, NNODES);

    // mean pool + final linear
    colsum_part_kernel<<<128, 256, 0, stream>>>(hb1, part, NNODES);
    final_kernel<<<1, 64, 0, stream>>>(part, Wout, bout, out, 128);
}